// Round 7
// baseline (308.211 us; speedup 1.0000x reference)
//
#include <hip/hip_runtime.h>

typedef unsigned short ushort_t;
typedef unsigned int uint_t;

typedef float f32x4_t __attribute__((ext_vector_type(4)));
typedef short s16x8_t __attribute__((ext_vector_type(8)));

#define NB   256   // B
#define NG   512   // 2*B graphs
#define NPG  24    // nodes per graph
#define NMAXI 32   // N_MAX
#define EPG  200   // edges per graph
#define DD   256   // feature dim
// 1/TEMPERATURE * log2(e) = 10 * 1.4426950408889634
#define L2E_OVER_T 14.426950408889634f

__device__ __forceinline__ ushort_t f2bf(float f) {
    uint_t u = __float_as_uint(f);
    u += 0x7FFFu + ((u >> 16) & 1u);        // round-to-nearest-even
    return (ushort_t)(u >> 16);
}
__device__ __forceinline__ float bfhi(uint_t u) { return __uint_as_float(u & 0xFFFF0000u); }
__device__ __forceinline__ float bflo(uint_t u) { return __uint_as_float(u << 16); }

__device__ __forceinline__ float frcp(float x) {
#if __has_builtin(__builtin_amdgcn_rcpf)
    return __builtin_amdgcn_rcpf(x);
#else
    return 1.0f / x;
#endif
}

// ---------------------------------------------------------------------------
// Kernel A: W1,W2 -> bf16 transposed ([n][k]), via LDS transpose.
// ---------------------------------------------------------------------------
__global__ __launch_bounds__(256) void prep_w(const float* __restrict__ W1,
                                              const float* __restrict__ W2,
                                              ushort_t* __restrict__ W1T,
                                              ushort_t* __restrict__ W2T)
{
    __shared__ float tile[2][4 * 256];
    const int t = threadIdx.x;
    const int k0 = blockIdx.x * 4;
    #pragma unroll
    for (int i = t; i < 4 * 256; i += 256) {
        tile[0][i] = W1[k0 * 256 + i];
        tile[1][i] = W2[k0 * 256 + i];
    }
    __syncthreads();
    const int n = t;
    #pragma unroll
    for (int m = 0; m < 2; ++m) {
        uint_t p0 = (uint_t)f2bf(tile[m][0 * 256 + n]) | ((uint_t)f2bf(tile[m][1 * 256 + n]) << 16);
        uint_t p1 = (uint_t)f2bf(tile[m][2 * 256 + n]) | ((uint_t)f2bf(tile[m][3 * 256 + n]) << 16);
        ushort_t* dst = (m ? W2T : W1T) + n * 256 + k0;
        uint2 pk; pk.x = p0; pk.y = p1;
        *(uint2*)dst = pk;
    }
}

// ---------------------------------------------------------------------------
// Kernel B: fused 2-layer MLP on the 12288 surviving edge rows (rank < 24).
// ---------------------------------------------------------------------------
__global__ __launch_bounds__(256) void mlp_kernel(
    const float* __restrict__ X, const ushort_t* __restrict__ W1T,
    const ushort_t* __restrict__ W2T, const float* __restrict__ b1,
    const float* __restrict__ b2, float* __restrict__ Y)
{
    __shared__ ushort_t sA[64 * 272];
    const int t = threadIdx.x;
    const int blk = blockIdx.x;
    const int lane = t & 63;
    const int w = t >> 6;
    const int quad = lane >> 4;
    const int mrow = lane & 15;

    {
        int r = t >> 2;
        int ch = (t & 3) * 64;
        int rho = blk * 64 + r;
        int g = rho / NPG;
        int e = rho - g * NPG;
        const float* src = X + ((size_t)(g * EPG + e)) * DD + ch;
        ushort_t* dst = &sA[r * 272 + ch];
        #pragma unroll
        for (int i = 0; i < 8; ++i) {
            float4 v0 = *(const float4*)(src + i * 8);
            float4 v1 = *(const float4*)(src + i * 8 + 4);
            uint4 pk;
            pk.x = (uint_t)f2bf(v0.x) | ((uint_t)f2bf(v0.y) << 16);
            pk.y = (uint_t)f2bf(v0.z) | ((uint_t)f2bf(v0.w) << 16);
            pk.z = (uint_t)f2bf(v1.x) | ((uint_t)f2bf(v1.y) << 16);
            pk.w = (uint_t)f2bf(v1.z) | ((uint_t)f2bf(v1.w) << 16);
            *(uint4*)(dst + i * 8) = pk;
        }
    }
    __syncthreads();

    f32x4_t acc[16];
    #pragma unroll
    for (int i = 0; i < 16; ++i) acc[i] = (f32x4_t){0.f, 0.f, 0.f, 0.f};

    #pragma unroll
    for (int k0 = 0; k0 < 256; k0 += 32) {
        s16x8_t a[4], bb[4];
        #pragma unroll
        for (int mt = 0; mt < 4; ++mt)
            a[mt] = *(const s16x8_t*)&sA[(mt * 16 + mrow) * 272 + k0 + quad * 8];
        #pragma unroll
        for (int nt = 0; nt < 4; ++nt)
            bb[nt] = *(const s16x8_t*)(W1T + (size_t)(64 * w + nt * 16 + mrow) * 256 + k0 + quad * 8);
        #pragma unroll
        for (int mt = 0; mt < 4; ++mt) {
            #pragma unroll
            for (int nt = 0; nt < 4; ++nt)
                acc[mt * 4 + nt] = __builtin_amdgcn_mfma_f32_16x16x32_bf16(
                    a[mt], bb[nt], acc[mt * 4 + nt], 0, 0, 0);
        }
    }
    __syncthreads();

    #pragma unroll
    for (int nt = 0; nt < 4; ++nt) {
        int col = 64 * w + nt * 16 + mrow;
        float bias = b1[col];
        #pragma unroll
        for (int mt = 0; mt < 4; ++mt) {
            f32x4_t v = acc[mt * 4 + nt];
            #pragma unroll
            for (int reg = 0; reg < 4; ++reg) {
                int row = mt * 16 + quad * 4 + reg;
                sA[row * 272 + col] = f2bf(fmaxf(v[reg] + bias, 0.f));
            }
        }
    }
    __syncthreads();

    #pragma unroll
    for (int i = 0; i < 16; ++i) acc[i] = (f32x4_t){0.f, 0.f, 0.f, 0.f};

    #pragma unroll
    for (int k0 = 0; k0 < 256; k0 += 32) {
        s16x8_t a[4], bb[4];
        #pragma unroll
        for (int mt = 0; mt < 4; ++mt)
            a[mt] = *(const s16x8_t*)&sA[(mt * 16 + mrow) * 272 + k0 + quad * 8];
        #pragma unroll
        for (int nt = 0; nt < 4; ++nt)
            bb[nt] = *(const s16x8_t*)(W2T + (size_t)(64 * w + nt * 16 + mrow) * 256 + k0 + quad * 8);
        #pragma unroll
        for (int mt = 0; mt < 4; ++mt) {
            #pragma unroll
            for (int nt = 0; nt < 4; ++nt)
                acc[mt * 4 + nt] = __builtin_amdgcn_mfma_f32_16x16x32_bf16(
                    a[mt], bb[nt], acc[mt * 4 + nt], 0, 0, 0);
        }
    }

    #pragma unroll
    for (int nt = 0; nt < 4; ++nt) {
        int col = 64 * w + nt * 16 + mrow;
        float bias = b2[col];
        #pragma unroll
        for (int mt = 0; mt < 4; ++mt) {
            f32x4_t v = acc[mt * 4 + nt];
            #pragma unroll
            for (int reg = 0; reg < 4; ++reg) {
                int row = blk * 64 + mt * 16 + quad * 4 + reg;
                Y[(size_t)row * 256 + col] = v[reg] + bias;
            }
        }
    }
}

// ---------------------------------------------------------------------------
// Kernel C: per-b fused K-build -> 20x linear-domain Sinkhorn -> MFMA score.
// 512 threads (8 waves): LDS 58.9 KB -> 2 blocks/CU occupancy target ->
// 4 waves/SIMD -> VGPR budget 128 (the 1024-thr version was hard-capped at 64
// and spilled ~40 regs/thread; rounds 2-6 evidence).
// Thread (R = t>>4 in 0..31, C = t&15) owns the 8x16 K tile, packed bf16 in
// Kp[8][8] (64 uints). Peak live ~108 regs -> no scratch.
//   row step: 8 row-partials over 16 cols, shfl_xor(1,2,4,8) over C lanes
//   col step: 16 col-partials over 8 rows, shfl_xor(16,32) over the wave's
//             4 R values + 8-entry LDS Vp second stage
//   score:    MFMA 16x16x32 on plan(bf16 LDS) x cf^T(bf16 LDS)
// ---------------------------------------------------------------------------
__global__ __launch_bounds__(512) void sink_kernel(
    const float* __restrict__ Tplan, const int* __restrict__ from_idx,
    const int* __restrict__ to_idx, const int* __restrict__ qsz,
    const int* __restrict__ csz, const float* __restrict__ qcf,
    float* __restrict__ out)
{
    const int b = blockIdx.x;
    const int t = threadIdx.x;
    const int R = t >> 4;      // row group: rows 8R..8R+7
    const int C = t & 15;      // col group: cols 16C..16C+15
    const int w = t >> 6;      // wave id 0..7 (rows 32w..32w+31)

    // overlay region (phase-disjoint):
    //  build: Tl (33*33 f) @0, fq/tq/fc/tc @4368/5392/6416/7440
    //  iters: Vp [8][272] f @0 (8704 B)
    //  score: planb [256][40] bf16 @0 (20480 B), cftb [256][40] bf16 @20480
    __shared__ __align__(16) char ovl[56320];
    __shared__ float ru_s[260];
    __shared__ float rv_p[320];    // col chunk C at rv_p[20C..20C+15]
    __shared__ float wsum[8];

    float* Tl = (float*)ovl;
    int* fq = (int*)(ovl + 4368);
    int* tq = (int*)(ovl + 5392);
    int* fc = (int*)(ovl + 6416);
    int* tc = (int*)(ovl + 7440);
    float* Vp = (float*)ovl;                   // [8][272]
    ushort_t* planb = (ushort_t*)ovl;          // [256][40] bf16
    ushort_t* cftb  = (ushort_t*)(ovl + 20480);// [256][40] bf16 (n=col, k=j)

    // --- phase 1: init ---
    for (int i = t; i < 33 * 33; i += 512) Tl[i] = 0.f;
    if (t < 320) rv_p[t] = 1.0f;
    if (t < 256) {
        int gq = 2 * b, gc = 2 * b + 1;
        int a = NMAXI, bb = NMAXI, c = NMAXI, d = NMAXI;
        if (t < EPG) {
            a  = from_idx[gq * EPG + t] - gq * NPG;
            bb = to_idx  [gq * EPG + t] - gq * NPG;
            c  = from_idx[gc * EPG + t] - gc * NPG;
            d  = to_idx  [gc * EPG + t] - gc * NPG;
        }
        fq[t] = a; tq[t] = bb; fc[t] = c; tc[t] = d;
    }
    __syncthreads();
    {   // fill T interior (two rows per thread)
        #pragma unroll
        for (int h = 0; h < 2; ++h) {
            int idx = t + 512 * h;
            int i = idx >> 5, j = idx & 31;
            Tl[i * 33 + j] = Tplan[((size_t)b << 10) + idx];
        }
    }
    __syncthreads();

    // --- build K tile: i-outer (only one row's pointers live at a time) ---
    uint_t Kp[8][8];
    #pragma unroll
    for (int i = 0; i < 8; ++i) {
        const float* T1 = &Tl[fq[8 * R + i] * 33];
        const float* T2 = &Tl[tq[8 * R + i] * 33];
        #pragma unroll
        for (int u = 0; u < 8; ++u) {
            int c0 = 16 * C + 2 * u;
            int f0 = fc[c0], t0 = tc[c0];
            int f1 = fc[c0 + 1], t1 = tc[c0 + 1];
            float la0 = T1[f0] * T2[t0] + T1[t0] * T2[f0];
            float la1 = T1[f1] * T2[t1] + T1[t1] * T2[f1];
            Kp[i][u] = (uint_t)f2bf(exp2f(la0 * L2E_OVER_T))
                     | ((uint_t)f2bf(exp2f(la1 * L2E_OVER_T)) << 16);
        }
    }

    // --- 20 Sinkhorn iterations ---
    for (int it = 0; it < 20; ++it) {
        // row step: U_r = sum_j K[r][j] * rv[j], r = 8R..8R+7
        {
            float4 rv0 = *(const float4*)&rv_p[20 * C + 0];
            float4 rv1 = *(const float4*)&rv_p[20 * C + 4];
            float4 rv2 = *(const float4*)&rv_p[20 * C + 8];
            float4 rv3 = *(const float4*)&rv_p[20 * C + 12];
            #pragma unroll
            for (int i = 0; i < 8; ++i) {
                float a0 = bflo(Kp[i][0]) * rv0.x + bfhi(Kp[i][0]) * rv0.y;
                float a1 = bflo(Kp[i][1]) * rv0.z + bfhi(Kp[i][1]) * rv0.w;
                float a2 = bflo(Kp[i][2]) * rv1.x + bfhi(Kp[i][2]) * rv1.y;
                float a3 = bflo(Kp[i][3]) * rv1.z + bfhi(Kp[i][3]) * rv1.w;
                a0 += bflo(Kp[i][4]) * rv2.x + bfhi(Kp[i][4]) * rv2.y;
                a1 += bflo(Kp[i][5]) * rv2.z + bfhi(Kp[i][5]) * rv2.w;
                a2 += bflo(Kp[i][6]) * rv3.x + bfhi(Kp[i][6]) * rv3.y;
                a3 += bflo(Kp[i][7]) * rv3.z + bfhi(Kp[i][7]) * rv3.w;
                float s = (a0 + a1) + (a2 + a3);
                s += __shfl_xor(s, 1);
                s += __shfl_xor(s, 2);
                s += __shfl_xor(s, 4);
                s += __shfl_xor(s, 8);
                if (C == 0) ru_s[8 * R + i] = frcp(s);
            }
        }
        __syncthreads();
        // col step: V_j = sum_i K[i][j] * ru[i]
        {
            float pc[16];
            #pragma unroll
            for (int u = 0; u < 8; ++u) { pc[2 * u] = 0.f; pc[2 * u + 1] = 0.f; }
            #pragma unroll
            for (int i = 0; i < 8; ++i) {
                float ui = ru_s[8 * R + i];
                #pragma unroll
                for (int u = 0; u < 8; ++u) {
                    pc[2 * u]     += bflo(Kp[i][u]) * ui;
                    pc[2 * u + 1] += bfhi(Kp[i][u]) * ui;
                }
            }
            #pragma unroll
            for (int k = 0; k < 16; ++k) {
                float s = pc[k];
                s += __shfl_xor(s, 16);
                s += __shfl_xor(s, 32);
                pc[k] = s;
            }
            if ((t & 63) < 16) {   // lane<16 covers all 16 C values of this wave
                float* dst = &Vp[w * 272 + C * 16];
                *(float4*)(dst + 0)  = (float4){pc[0], pc[1], pc[2], pc[3]};
                *(float4*)(dst + 4)  = (float4){pc[4], pc[5], pc[6], pc[7]};
                *(float4*)(dst + 8)  = (float4){pc[8], pc[9], pc[10], pc[11]};
                *(float4*)(dst + 12) = (float4){pc[12], pc[13], pc[14], pc[15]};
            }
        }
        __syncthreads();
        if (t < 256) {   // second stage: sum the 8 wave partials
            float s = 0.f;
            #pragma unroll
            for (int ww = 0; ww < 8; ++ww) s += Vp[ww * 272 + t];
            rv_p[(t >> 4) * 20 + (t & 15)] = frcp(s);
        }
        __syncthreads();
    }

    // --- score phase: PC = plan(256x32) @ cf^T via MFMA ---
    int nq = qsz[b]; if (nq > 24) nq = 24;
    int nc = csz[b]; if (nc > 24) nc = 24;

    // zero planb + cftb (40960 B = 10240 u32)
    {
        uint_t* z = (uint_t*)ovl;
        #pragma unroll
        for (int k = 0; k < 20; ++k) z[t + 512 * k] = 0u;
    }
    __syncthreads();

    // fill planb: thread (R, C<2) writes rows 8R..8R+7, col pairs
    if (C < 2) {
        int umax = (C == 0) ? 8 : 4;
        #pragma unroll
        for (int i = 0; i < 8; ++i) {
            int row = 8 * R + i;
            float rr = ru_s[row];
            for (int u = 0; u < umax; ++u) {
                int j = 16 * C + 2 * u;
                float p0 = (j < nc)     ? bflo(Kp[i][u]) * rr * rv_p[20 * C + 2 * u]     : 0.f;
                float p1 = (j + 1 < nc) ? bfhi(Kp[i][u]) * rr * rv_p[20 * C + 2 * u + 1] : 0.f;
                *(uint_t*)(planb + row * 40 + j) =
                    (uint_t)f2bf(p0) | ((uint_t)f2bf(p1) << 16);
            }
        }
    }
    // fill cftb: transpose cf rows (<24) into [n=col][k=j] bf16
    #pragma unroll
    for (int h = 0; h < 2; ++h) {
        int idx = t + 512 * h;
        if (idx < 768) {
            int j = idx >> 5, inner = idx & 31;
            int c0 = inner * 8;
            const float* src = qcf + ((size_t)(2 * b + 1) * 24 + j) * 256 + c0;
            float4 v0 = *(const float4*)(src);
            float4 v1 = *(const float4*)(src + 4);
            cftb[(c0 + 0) * 40 + j] = f2bf(v0.x);
            cftb[(c0 + 1) * 40 + j] = f2bf(v0.y);
            cftb[(c0 + 2) * 40 + j] = f2bf(v0.z);
            cftb[(c0 + 3) * 40 + j] = f2bf(v0.w);
            cftb[(c0 + 4) * 40 + j] = f2bf(v1.x);
            cftb[(c0 + 5) * 40 + j] = f2bf(v1.y);
            cftb[(c0 + 6) * 40 + j] = f2bf(v1.z);
            cftb[(c0 + 7) * 40 + j] = f2bf(v1.w);
        }
    }
    __syncthreads();

    // MFMA: wave w -> row tiles 2w, 2w+1 (rows 32w..32w+31), all 16 col tiles
    const int lane = t & 63;
    const int mrow = lane & 15;
    const int quad = lane >> 4;
    float ssum = 0.f;
    {
        const float* qbase = qcf + (size_t)(2 * b) * 24 * 256;
        s16x8_t a0 = *(const s16x8_t*)(planb + (32 * w + mrow) * 40 + quad * 8);
        s16x8_t a1 = *(const s16x8_t*)(planb + (32 * w + 16 + mrow) * 40 + quad * 8);
        #pragma unroll
        for (int nt = 0; nt < 16; ++nt) {
            s16x8_t bbf = *(const s16x8_t*)(cftb + (16 * nt + mrow) * 40 + quad * 8);
            int col = 16 * nt + mrow;
            f32x4_t acc = (f32x4_t){0.f, 0.f, 0.f, 0.f};
            acc = __builtin_amdgcn_mfma_f32_16x16x32_bf16(a0, bbf, acc, 0, 0, 0);
            #pragma unroll
            for (int reg = 0; reg < 4; ++reg) {
                int row = 32 * w + quad * 4 + reg;
                if (row < nq) {
                    float qv = qbase[(size_t)row * 256 + col];
                    ssum += fmaxf(qv - acc[reg], 0.f);
                } else {
                    ssum += fmaxf(-acc[reg], 0.f);
                }
            }
            acc = (f32x4_t){0.f, 0.f, 0.f, 0.f};
            acc = __builtin_amdgcn_mfma_f32_16x16x32_bf16(a1, bbf, acc, 0, 0, 0);
            #pragma unroll
            for (int reg = 0; reg < 4; ++reg) {
                int row = 32 * w + 16 + quad * 4 + reg;
                if (row < nq) {
                    float qv = qbase[(size_t)row * 256 + col];
                    ssum += fmaxf(qv - acc[reg], 0.f);
                } else {
                    ssum += fmaxf(-acc[reg], 0.f);
                }
            }
        }
    }
    ssum += __shfl_xor(ssum, 1);
    ssum += __shfl_xor(ssum, 2);
    ssum += __shfl_xor(ssum, 4);
    ssum += __shfl_xor(ssum, 8);
    ssum += __shfl_xor(ssum, 16);
    ssum += __shfl_xor(ssum, 32);
    if (lane == 0) wsum[w] = ssum;
    __syncthreads();
    if (t == 0) {
        float s = 0.f;
        #pragma unroll
        for (int i = 0; i < 8; ++i) s += wsum[i];
        out[b] = -s;
    }
}

// ---------------------------------------------------------------------------
extern "C" void kernel_launch(void* const* d_in, const int* in_sizes, int n_in,
                              void* d_out, int out_size, void* d_ws, size_t ws_size,
                              hipStream_t stream)
{
    const float* edge_feat = (const float*)d_in[0];
    const float* tplan     = (const float*)d_in[1];
    const float* W1        = (const float*)d_in[2];
    const float* b1        = (const float*)d_in[3];
    const float* W2        = (const float*)d_in[4];
    const float* b2        = (const float*)d_in[5];
    const int*   from_idx  = (const int*)d_in[6];
    const int*   to_idx    = (const int*)d_in[7];
    const int*   qsz       = (const int*)d_in[9];
    const int*   csz       = (const int*)d_in[10];
    float* out = (float*)d_out;

    // workspace: [0,128K) W1T bf16 | [128K,256K) W2T bf16 | [256K,+12.6MB) qcf f32
    char* ws = (char*)d_ws;
    ushort_t* W1T = (ushort_t*)ws;
    ushort_t* W2T = W1T + 65536;
    float* qcf = (float*)(ws + 262144);

    prep_w<<<64, 256, 0, stream>>>(W1, W2, W1T, W2T);
    mlp_kernel<<<192, 256, 0, stream>>>(edge_feat, W1T, W2T, b1, b2, qcf);
    sink_kernel<<<256, 512, 0, stream>>>(tplan, from_idx, to_idx, qsz, csz, qcf, out);
}

// Round 8
// 274.405 us; speedup vs baseline: 1.1232x; 1.1232x over previous
//
#include <hip/hip_runtime.h>

typedef unsigned short ushort_t;
typedef unsigned int uint_t;

typedef float f32x4_t __attribute__((ext_vector_type(4)));
typedef short s16x8_t __attribute__((ext_vector_type(8)));

#define NB   256   // B
#define NG   512   // 2*B graphs
#define NPG  24    // nodes per graph
#define NMAXI 32   // N_MAX
#define EPG  200   // edges per graph
#define DD   256   // feature dim
// 1/TEMPERATURE * log2(e) = 10 * 1.4426950408889634
#define L2E_OVER_T 14.426950408889634f

__device__ __forceinline__ ushort_t f2bf(float f) {
    uint_t u = __float_as_uint(f);
    u += 0x7FFFu + ((u >> 16) & 1u);        // round-to-nearest-even
    return (ushort_t)(u >> 16);
}
__device__ __forceinline__ float bfhi(uint_t u) { return __uint_as_float(u & 0xFFFF0000u); }
__device__ __forceinline__ float bflo(uint_t u) { return __uint_as_float(u << 16); }

__device__ __forceinline__ float frcp(float x) {
#if __has_builtin(__builtin_amdgcn_rcpf)
    return __builtin_amdgcn_rcpf(x);
#else
    return 1.0f / x;
#endif
}

// ---------------------------------------------------------------------------
// Kernel A: W1,W2 -> bf16 transposed ([n][k]), via LDS transpose.
// ---------------------------------------------------------------------------
__global__ __launch_bounds__(256) void prep_w(const float* __restrict__ W1,
                                              const float* __restrict__ W2,
                                              ushort_t* __restrict__ W1T,
                                              ushort_t* __restrict__ W2T)
{
    __shared__ float tile[2][4 * 256];
    const int t = threadIdx.x;
    const int k0 = blockIdx.x * 4;
    #pragma unroll
    for (int i = t; i < 4 * 256; i += 256) {
        tile[0][i] = W1[k0 * 256 + i];
        tile[1][i] = W2[k0 * 256 + i];
    }
    __syncthreads();
    const int n = t;
    #pragma unroll
    for (int m = 0; m < 2; ++m) {
        uint_t p0 = (uint_t)f2bf(tile[m][0 * 256 + n]) | ((uint_t)f2bf(tile[m][1 * 256 + n]) << 16);
        uint_t p1 = (uint_t)f2bf(tile[m][2 * 256 + n]) | ((uint_t)f2bf(tile[m][3 * 256 + n]) << 16);
        ushort_t* dst = (m ? W2T : W1T) + n * 256 + k0;
        uint2 pk; pk.x = p0; pk.y = p1;
        *(uint2*)dst = pk;
    }
}

// ---------------------------------------------------------------------------
// Kernel B: fused 2-layer MLP on the 12288 surviving edge rows (rank < 24).
// ---------------------------------------------------------------------------
__global__ __launch_bounds__(256) void mlp_kernel(
    const float* __restrict__ X, const ushort_t* __restrict__ W1T,
    const ushort_t* __restrict__ W2T, const float* __restrict__ b1,
    const float* __restrict__ b2, float* __restrict__ Y)
{
    __shared__ ushort_t sA[64 * 272];
    const int t = threadIdx.x;
    const int blk = blockIdx.x;
    const int lane = t & 63;
    const int w = t >> 6;
    const int quad = lane >> 4;
    const int mrow = lane & 15;

    {
        int r = t >> 2;
        int ch = (t & 3) * 64;
        int rho = blk * 64 + r;
        int g = rho / NPG;
        int e = rho - g * NPG;
        const float* src = X + ((size_t)(g * EPG + e)) * DD + ch;
        ushort_t* dst = &sA[r * 272 + ch];
        #pragma unroll
        for (int i = 0; i < 8; ++i) {
            float4 v0 = *(const float4*)(src + i * 8);
            float4 v1 = *(const float4*)(src + i * 8 + 4);
            uint4 pk;
            pk.x = (uint_t)f2bf(v0.x) | ((uint_t)f2bf(v0.y) << 16);
            pk.y = (uint_t)f2bf(v0.z) | ((uint_t)f2bf(v0.w) << 16);
            pk.z = (uint_t)f2bf(v1.x) | ((uint_t)f2bf(v1.y) << 16);
            pk.w = (uint_t)f2bf(v1.z) | ((uint_t)f2bf(v1.w) << 16);
            *(uint4*)(dst + i * 8) = pk;
        }
    }
    __syncthreads();

    f32x4_t acc[16];
    #pragma unroll
    for (int i = 0; i < 16; ++i) acc[i] = (f32x4_t){0.f, 0.f, 0.f, 0.f};

    #pragma unroll
    for (int k0 = 0; k0 < 256; k0 += 32) {
        s16x8_t a[4], bb[4];
        #pragma unroll
        for (int mt = 0; mt < 4; ++mt)
            a[mt] = *(const s16x8_t*)&sA[(mt * 16 + mrow) * 272 + k0 + quad * 8];
        #pragma unroll
        for (int nt = 0; nt < 4; ++nt)
            bb[nt] = *(const s16x8_t*)(W1T + (size_t)(64 * w + nt * 16 + mrow) * 256 + k0 + quad * 8);
        #pragma unroll
        for (int mt = 0; mt < 4; ++mt) {
            #pragma unroll
            for (int nt = 0; nt < 4; ++nt)
                acc[mt * 4 + nt] = __builtin_amdgcn_mfma_f32_16x16x32_bf16(
                    a[mt], bb[nt], acc[mt * 4 + nt], 0, 0, 0);
        }
    }
    __syncthreads();

    #pragma unroll
    for (int nt = 0; nt < 4; ++nt) {
        int col = 64 * w + nt * 16 + mrow;
        float bias = b1[col];
        #pragma unroll
        for (int mt = 0; mt < 4; ++mt) {
            f32x4_t v = acc[mt * 4 + nt];
            #pragma unroll
            for (int reg = 0; reg < 4; ++reg) {
                int row = mt * 16 + quad * 4 + reg;
                sA[row * 272 + col] = f2bf(fmaxf(v[reg] + bias, 0.f));
            }
        }
    }
    __syncthreads();

    #pragma unroll
    for (int i = 0; i < 16; ++i) acc[i] = (f32x4_t){0.f, 0.f, 0.f, 0.f};

    #pragma unroll
    for (int k0 = 0; k0 < 256; k0 += 32) {
        s16x8_t a[4], bb[4];
        #pragma unroll
        for (int mt = 0; mt < 4; ++mt)
            a[mt] = *(const s16x8_t*)&sA[(mt * 16 + mrow) * 272 + k0 + quad * 8];
        #pragma unroll
        for (int nt = 0; nt < 4; ++nt)
            bb[nt] = *(const s16x8_t*)(W2T + (size_t)(64 * w + nt * 16 + mrow) * 256 + k0 + quad * 8);
        #pragma unroll
        for (int mt = 0; mt < 4; ++mt) {
            #pragma unroll
            for (int nt = 0; nt < 4; ++nt)
                acc[mt * 4 + nt] = __builtin_amdgcn_mfma_f32_16x16x32_bf16(
                    a[mt], bb[nt], acc[mt * 4 + nt], 0, 0, 0);
        }
    }

    #pragma unroll
    for (int nt = 0; nt < 4; ++nt) {
        int col = 64 * w + nt * 16 + mrow;
        float bias = b2[col];
        #pragma unroll
        for (int mt = 0; mt < 4; ++mt) {
            f32x4_t v = acc[mt * 4 + nt];
            #pragma unroll
            for (int reg = 0; reg < 4; ++reg) {
                int row = blk * 64 + mt * 16 + quad * 4 + reg;
                Y[(size_t)row * 256 + col] = v[reg] + bias;
            }
        }
    }
}

// ---------------------------------------------------------------------------
// Kernel C: per-b fused K-build -> 20x linear-domain Sinkhorn -> MFMA score.
// 1024 threads (16 waves/CU occupancy; VGPR hard-capped at 64 by the
// LDS-implied occupancy — rounds 2-7 evidence). Thread (R=t>>4, C=t&15) owns
// the 4x16 K tile packed bf16 in Kp[4][8] (32 uints). Every loop phase is
// engineered to <= ~45 live VGPRs so the 64 cap does NOT spill:
//   row step: g-outer (one rv float4 live), pr[4] accumulators
//   col step: two 8-column halves (pc[8]), shfl_xor(16,32) + LDS Vp 2-stage
//   score:    MFMA 16x16x32 on plan(bf16 LDS) x cf^T(bf16 LDS)
// ---------------------------------------------------------------------------
__global__ __launch_bounds__(1024) void sink_kernel(
    const float* __restrict__ Tplan, const int* __restrict__ from_idx,
    const int* __restrict__ to_idx, const int* __restrict__ qsz,
    const int* __restrict__ csz, const float* __restrict__ qcf,
    float* __restrict__ out)
{
    const int b = blockIdx.x;
    const int t = threadIdx.x;
    const int R = t >> 4;      // row group: rows 4R..4R+3
    const int C = t & 15;      // col group: cols 16C..16C+15
    const int w = t >> 6;      // wave id 0..15 (rows 16w..16w+15)

    // overlay region (phase-disjoint):
    //  build: Tl (33*33 f) @0, fq/tq/fc/tc @4368/5392/6416/7440
    //  iters: Vp [16][272] f @0 (17408 B)
    //  score: planb [256][40] bf16 @0 (20480 B), cftb [256][40] bf16 @20480
    __shared__ __align__(16) char ovl[56320];
    __shared__ float ru_s[260];
    __shared__ float rv_p[320];    // col chunk C at rv_p[20C..20C+15]
    __shared__ float wsum[16];

    float* Tl = (float*)ovl;
    int* fq = (int*)(ovl + 4368);
    int* tq = (int*)(ovl + 5392);
    int* fc = (int*)(ovl + 6416);
    int* tc = (int*)(ovl + 7440);
    float* Vp = (float*)ovl;                   // [16][272]
    ushort_t* planb = (ushort_t*)ovl;          // [256][40] bf16
    ushort_t* cftb  = (ushort_t*)(ovl + 20480);// [256][40] bf16 (n=col, k=j)

    // --- phase 1: init ---
    for (int i = t; i < 33 * 33; i += 1024) Tl[i] = 0.f;
    if (t < 320) rv_p[t] = 1.0f;
    if (t < 256) {
        int gq = 2 * b, gc = 2 * b + 1;
        int a = NMAXI, bb = NMAXI, c = NMAXI, d = NMAXI;
        if (t < EPG) {
            a  = from_idx[gq * EPG + t] - gq * NPG;
            bb = to_idx  [gq * EPG + t] - gq * NPG;
            c  = from_idx[gc * EPG + t] - gc * NPG;
            d  = to_idx  [gc * EPG + t] - gc * NPG;
        }
        fq[t] = a; tq[t] = bb; fc[t] = c; tc[t] = d;
    }
    __syncthreads();
    {
        int i = t >> 5, j = t & 31;
        Tl[i * 33 + j] = Tplan[((size_t)b << 10) + t];
    }
    __syncthreads();

    // --- build K tile: i-outer (2 pointers + Kp live; ~45 regs peak) ---
    uint_t Kp[4][8];
    #pragma unroll
    for (int i = 0; i < 4; ++i) {
        const float* T1 = &Tl[fq[4 * R + i] * 33];
        const float* T2 = &Tl[tq[4 * R + i] * 33];
        #pragma unroll
        for (int u = 0; u < 8; ++u) {
            int c0 = 16 * C + 2 * u;
            int f0 = fc[c0], t0 = tc[c0];
            int f1 = fc[c0 + 1], t1 = tc[c0 + 1];
            float la0 = T1[f0] * T2[t0] + T1[t0] * T2[f0];
            float la1 = T1[f1] * T2[t1] + T1[t1] * T2[f1];
            Kp[i][u] = (uint_t)f2bf(exp2f(la0 * L2E_OVER_T))
                     | ((uint_t)f2bf(exp2f(la1 * L2E_OVER_T)) << 16);
        }
    }

    // --- 20 Sinkhorn iterations ---
    for (int it = 0; it < 20; ++it) {
        // row step: U_r = sum_j K[r][j] * rv[j]; g-outer keeps 1 rv4 live
        {
            float pr[4] = {0.f, 0.f, 0.f, 0.f};
            #pragma unroll
            for (int g = 0; g < 4; ++g) {
                float4 rv = *(const float4*)&rv_p[20 * C + 4 * g];
                #pragma unroll
                for (int i = 0; i < 4; ++i) {
                    pr[i] += bflo(Kp[i][2 * g]) * rv.x + bfhi(Kp[i][2 * g]) * rv.y
                           + bflo(Kp[i][2 * g + 1]) * rv.z + bfhi(Kp[i][2 * g + 1]) * rv.w;
                }
            }
            #pragma unroll
            for (int i = 0; i < 4; ++i) {
                float s = pr[i];
                s += __shfl_xor(s, 1);
                s += __shfl_xor(s, 2);
                s += __shfl_xor(s, 4);
                s += __shfl_xor(s, 8);
                if (C == 0) ru_s[4 * R + i] = frcp(s);
            }
        }
        __syncthreads();
        // col step: V_j = sum_i K[i][j] * ru[i]; two 8-col halves (pc[8])
        #pragma unroll
        for (int h = 0; h < 2; ++h) {
            float pc[8] = {0.f, 0.f, 0.f, 0.f, 0.f, 0.f, 0.f, 0.f};
            #pragma unroll
            for (int i = 0; i < 4; ++i) {
                float ui = ru_s[4 * R + i];
                #pragma unroll
                for (int u = 0; u < 4; ++u) {
                    uint_t k = Kp[i][4 * h + u];
                    pc[2 * u]     += bflo(k) * ui;
                    pc[2 * u + 1] += bfhi(k) * ui;
                }
            }
            #pragma unroll
            for (int k = 0; k < 8; ++k) {
                float s = pc[k];
                s += __shfl_xor(s, 16);
                s += __shfl_xor(s, 32);
                pc[k] = s;
            }
            if ((t & 63) < 16) {   // lane<16 covers all 16 C values of this wave
                float* dst = &Vp[w * 272 + C * 16 + 8 * h];
                *(float4*)(dst + 0) = (float4){pc[0], pc[1], pc[2], pc[3]};
                *(float4*)(dst + 4) = (float4){pc[4], pc[5], pc[6], pc[7]};
            }
        }
        __syncthreads();
        if (t < 256) {   // second stage: sum the 16 wave partials
            float s = 0.f;
            #pragma unroll
            for (int ww = 0; ww < 16; ++ww) s += Vp[ww * 272 + t];
            rv_p[(t >> 4) * 20 + (t & 15)] = frcp(s);
        }
        __syncthreads();
    }

    // --- score phase: PC = plan(256x32) @ cf^T via MFMA ---
    int nq = qsz[b]; if (nq > 24) nq = 24;
    int nc = csz[b]; if (nc > 24) nc = 24;

    // zero planb + cftb (40960 B = 10240 u32)
    {
        uint_t* z = (uint_t*)ovl;
        #pragma unroll
        for (int k = 0; k < 10; ++k) z[t + 1024 * k] = 0u;
    }
    __syncthreads();

    // fill planb: thread (R, C<2) writes rows 4R..4R+3, col pairs
    if (C < 2) {
        int umax = (C == 0) ? 8 : 4;
        #pragma unroll
        for (int i = 0; i < 4; ++i) {
            int row = 4 * R + i;
            float rr = ru_s[row];
            for (int u = 0; u < umax; ++u) {
                int j = 16 * C + 2 * u;
                float p0 = (j < nc)     ? bflo(Kp[i][u]) * rr * rv_p[20 * C + 2 * u]     : 0.f;
                float p1 = (j + 1 < nc) ? bfhi(Kp[i][u]) * rr * rv_p[20 * C + 2 * u + 1] : 0.f;
                *(uint_t*)(planb + row * 40 + j) =
                    (uint_t)f2bf(p0) | ((uint_t)f2bf(p1) << 16);
            }
        }
    }
    // fill cftb: transpose cf rows (<24) into [n=col][k=j] bf16
    if (t < 768) {
        int j = t >> 5, inner = t & 31;
        int c0 = inner * 8;
        const float* src = qcf + ((size_t)(2 * b + 1) * 24 + j) * 256 + c0;
        float4 v0 = *(const float4*)(src);
        float4 v1 = *(const float4*)(src + 4);
        cftb[(c0 + 0) * 40 + j] = f2bf(v0.x);
        cftb[(c0 + 1) * 40 + j] = f2bf(v0.y);
        cftb[(c0 + 2) * 40 + j] = f2bf(v0.z);
        cftb[(c0 + 3) * 40 + j] = f2bf(v0.w);
        cftb[(c0 + 4) * 40 + j] = f2bf(v1.x);
        cftb[(c0 + 5) * 40 + j] = f2bf(v1.y);
        cftb[(c0 + 6) * 40 + j] = f2bf(v1.z);
        cftb[(c0 + 7) * 40 + j] = f2bf(v1.w);
    }
    __syncthreads();

    // MFMA: wave w -> row tile w (rows 16w..16w+15), all 16 col tiles
    const int lane = t & 63;
    const int mrow = lane & 15;
    const int quad = lane >> 4;
    float ssum = 0.f;
    {
        const float* qbase = qcf + (size_t)(2 * b) * 24 * 256;
        s16x8_t a = *(const s16x8_t*)(planb + (16 * w + mrow) * 40 + quad * 8);
        #pragma unroll
        for (int nt = 0; nt < 16; ++nt) {
            s16x8_t bbf = *(const s16x8_t*)(cftb + (16 * nt + mrow) * 40 + quad * 8);
            f32x4_t acc = (f32x4_t){0.f, 0.f, 0.f, 0.f};
            acc = __builtin_amdgcn_mfma_f32_16x16x32_bf16(a, bbf, acc, 0, 0, 0);
            int col = 16 * nt + mrow;
            #pragma unroll
            for (int reg = 0; reg < 4; ++reg) {
                int row = 16 * w + quad * 4 + reg;
                if (row < nq) {
                    float qv = qbase[(size_t)row * 256 + col];
                    ssum += fmaxf(qv - acc[reg], 0.f);
                } else {
                    ssum += fmaxf(-acc[reg], 0.f);
                }
            }
        }
    }
    ssum += __shfl_xor(ssum, 1);
    ssum += __shfl_xor(ssum, 2);
    ssum += __shfl_xor(ssum, 4);
    ssum += __shfl_xor(ssum, 8);
    ssum += __shfl_xor(ssum, 16);
    ssum += __shfl_xor(ssum, 32);
    if (lane == 0) wsum[w] = ssum;
    __syncthreads();
    if (t == 0) {
        float s = 0.f;
        #pragma unroll
        for (int i = 0; i < 16; ++i) s += wsum[i];
        out[b] = -s;
    }
}

// ---------------------------------------------------------------------------
extern "C" void kernel_launch(void* const* d_in, const int* in_sizes, int n_in,
                              void* d_out, int out_size, void* d_ws, size_t ws_size,
                              hipStream_t stream)
{
    const float* edge_feat = (const float*)d_in[0];
    const float* tplan     = (const float*)d_in[1];
    const float* W1        = (const float*)d_in[2];
    const float* b1        = (const float*)d_in[3];
    const float* W2        = (const float*)d_in[4];
    const float* b2        = (const float*)d_in[5];
    const int*   from_idx  = (const int*)d_in[6];
    const int*   to_idx    = (const int*)d_in[7];
    const int*   qsz       = (const int*)d_in[9];
    const int*   csz       = (const int*)d_in[10];
    float* out = (float*)d_out;

    // workspace: [0,128K) W1T bf16 | [128K,256K) W2T bf16 | [256K,+12.6MB) qcf f32
    char* ws = (char*)d_ws;
    ushort_t* W1T = (ushort_t*)ws;
    ushort_t* W2T = W1T + 65536;
    float* qcf = (float*)(ws + 262144);

    prep_w<<<64, 256, 0, stream>>>(W1, W2, W1T, W2T);
    mlp_kernel<<<192, 256, 0, stream>>>(edge_feat, W1T, W2T, b1, b2, qcf);
    sink_kernel<<<256, 1024, 0, stream>>>(tplan, from_idx, to_idx, qsz, csz, qcf, out);
}